// Round 1
// baseline (21.874 us; speedup 1.0000x reference)
//
#include <hip/hip_runtime.h>
#include <hip/hip_fp16.h>
#include <stdint.h>

// out[8,8192] = x[8,8192] @ W.T, W[n,k] = nibble(Qidxs[n,k/8], INV[k%8]) - 7.5
// Single kernel: dequant-fused MFMA GEMM, K split into 32 chunks combined via atomicAdd.

typedef _Float16 half8 __attribute__((ext_vector_type(8)));
typedef float floatx16 __attribute__((ext_vector_type(16)));

union H2U { unsigned u; __half2 h; };
union V4H8 { uint4 u4; half8 h8; };

// (1024+n) exact -> -1024 -> -7.5  (all exact in f16)
__device__ __forceinline__ unsigned unpack_even(unsigned ws, __half2 c1, __half2 c2) {
    H2U t; t.u = (ws & 0x000F000Fu) | 0x64006400u;
    t.h = __hadd2(__hadd2(t.h, c1), c2);
    return t.u;
}
// (1024+16n) exact -> *1/16 - 71.5 = n - 7.5 (exact fma)
__device__ __forceinline__ unsigned unpack_odd(unsigned ws, __half2 cs, __half2 cc) {
    H2U t; t.u = (ws & 0x00F000F0u) | 0x64006400u;
    t.h = __hfma2(t.h, cs, cc);
    return t.u;
}

#define BPITCH 136                   // bytes per B-LDS row: 32 words + 8B pad (2-way-free b64 reads)
#define BREG   (32 * BPITCH)         // 4352 B per wave (32 n-rows)
#define STEPS  16                    // K=16 per mfma, 256 K per chunk
#define APITCH 272                   // 16 active slots + 1 zero slot, 16B each
#define LDS_BYTES (4 * BREG + STEPS * APITCH)   // 17408 + 4352 = 21760

__global__ __launch_bounds__(256, 4)
void hi4b_gemm(const float* __restrict__ x, const int* __restrict__ q,
               float* __restrict__ out)
{
    extern __shared__ char lds[];
    const int tid  = threadIdx.x;
    const int lane = tid & 63;
    const int wv   = tid >> 6;        // wave 0..3, each owns 32 n-rows
    const int bid  = blockIdx.x;
    const int ngroup = bid & 63;      // 64 groups of 128 n
    const int chunk  = bid >> 6;      // 32 K-chunks of 256 K

    const int nwave = ngroup * 128 + wv * 32;
    const int nlo = lane & 31;
    const int u   = lane >> 5;        // K-half group

    // ---------------- stage B: 32 rows x 32 packed words (4 KB) per wave ----------------
    {
        const int c  = lane & 7;      // uint4 (4 words) within row-chunk
        const int r0 = lane >> 3;     // 0..7
        const uint4* q4 = (const uint4*)q;
        const int base = (nwave + r0) * 256 + chunk * 8 + c;  // uint4 units, row=256 uint4
        uint4 v0 = q4[base];
        uint4 v1 = q4[base +  8 * 256];
        uint4 v2 = q4[base + 16 * 256];
        uint4 v3 = q4[base + 24 * 256];
        char* Bw = lds + wv * BREG;
        char* p0 = Bw + (r0     ) * BPITCH + c * 16;
        char* p1 = Bw + (r0 +  8) * BPITCH + c * 16;
        char* p2 = Bw + (r0 + 16) * BPITCH + c * 16;
        char* p3 = Bw + (r0 + 24) * BPITCH + c * 16;
        *(uint2*)(p0)     = make_uint2(v0.x, v0.y);
        *(uint2*)(p0 + 8) = make_uint2(v0.z, v0.w);
        *(uint2*)(p1)     = make_uint2(v1.x, v1.y);
        *(uint2*)(p1 + 8) = make_uint2(v1.z, v1.w);
        *(uint2*)(p2)     = make_uint2(v2.x, v2.y);
        *(uint2*)(p2 + 8) = make_uint2(v2.z, v2.w);
        *(uint2*)(p3)     = make_uint2(v3.x, v3.y);
        *(uint2*)(p3 + 8) = make_uint2(v3.z, v3.w);
    }

    // ---------------- stage A: compact f16 A-frag table [16 steps][16 slots][8 f16] ----------------
    char* Ab = lds + 4 * BREG;
    {
        const int s = tid >> 4, slot = tid & 15;
        const int uu = slot >> 3, r = slot & 7;      // batch row r (only 8 real rows)
        const int c0 = chunk * 256 + 16 * s + 4 * uu;
        const float4* x4 = (const float4*)x;
        float4 fa = x4[r * 2048 + (c0 >> 2)];        // k_local j=0..3  -> k = 4u+j
        float4 fb = x4[r * 2048 + ((c0 + 8) >> 2)];  // k_local j=4..7  -> k = 8+4u+j'
        __half2 h0 = __floats2half2_rn(fa.x, fa.y);
        __half2 h1 = __floats2half2_rn(fa.z, fa.w);
        __half2 h2 = __floats2half2_rn(fb.x, fb.y);
        __half2 h3 = __floats2half2_rn(fb.z, fb.w);
        H2U a0, a1, a2, a3; a0.h = h0; a1.h = h1; a2.h = h2; a3.h = h3;
        *(uint4*)(Ab + s * APITCH + slot * 16) = make_uint4(a0.u, a1.u, a2.u, a3.u);
        if (tid < STEPS)   // zero slot (A rows 8..31 are padding)
            *(uint4*)(Ab + tid * APITCH + 256) = make_uint4(0u, 0u, 0u, 0u);
    }
    __syncthreads();

    // ---------------- compute: 16 x mfma_f32_32x32x16_f16 ----------------
    const int brow = wv * BREG + nlo * BPITCH;
    const int aoff = 4 * BREG + ((nlo < 8) ? (u * 8 + nlo) * 16 : 256);
    const int sh = 8 * u;

    const __half2 c1 = __floats2half2_rn(-1024.0f, -1024.0f);
    const __half2 c2 = __floats2half2_rn(-7.5f, -7.5f);
    const __half2 cs = __floats2half2_rn(0.0625f, 0.0625f);
    const __half2 cc = __floats2half2_rn(-71.5f, -71.5f);

    floatx16 acc;
    #pragma unroll
    for (int i = 0; i < 16; ++i) acc[i] = 0.0f;

    #pragma unroll
    for (int s = 0; s < STEPS; ++s) {
        uint2 w2 = *(const uint2*)(lds + brow + s * 8);      // words 2s, 2s+1 of this n-row
        V4H8 A;  A.u4 = *(const uint4*)(lds + aoff + s * APITCH);
        unsigned wsa = w2.x >> sh;
        unsigned wsb = w2.y >> sh;
        V4H8 Bf;
        Bf.u4.x = unpack_even(wsa, c1, c2);   // k-local 4u+0, 4u+1   (nibbles 2u, 2u+4)
        Bf.u4.y = unpack_odd (wsa, cs, cc);   // k-local 4u+2, 4u+3   (nibbles 2u+1, 2u+5)
        Bf.u4.z = unpack_even(wsb, c1, c2);   // +8
        Bf.u4.w = unpack_odd (wsb, cs, cc);
        acc = __builtin_amdgcn_mfma_f32_32x32x16_f16(A.h8, Bf.h8, acc, 0, 0, 0);
    }

    // C/D: col = lane&31, row = reg + 4*(lane>>5) for regs 0..3  -> exactly b = 0..7
    float* op = out + nwave + nlo;
    #pragma unroll
    for (int r = 0; r < 4; ++r)
        atomicAdd(op + (r + 4 * u) * 8192, acc[r]);
}

extern "C" void kernel_launch(void* const* d_in, const int* in_sizes, int n_in,
                              void* d_out, int out_size, void* d_ws, size_t ws_size,
                              hipStream_t stream)
{
    const float* x = (const float*)d_in[0];
    const int*   q = (const int*)d_in[1];
    float* out = (float*)d_out;

    hipMemsetAsync(d_out, 0, (size_t)out_size * sizeof(float), stream);
    hipLaunchKernelGGL(hi4b_gemm, dim3(2048), dim3(256), LDS_BYTES, stream,
                       x, q, out);
}

// Round 2
// 17.309 us; speedup vs baseline: 1.2638x; 1.2638x over previous
//
#include <hip/hip_runtime.h>
#include <hip/hip_fp16.h>
#include <stdint.h>

// out[8,8192] = x[8,8192] @ W.T, W[n,k] = nibble(Qidxs[n,k/8], INV[k%8]) - 7.5
// Single kernel, no atomics, no memset:
//   grid = 256 blocks, block = 256 threads (4 waves).
//   Block owns 32 n-rows; wave w computes the K-quarter w (2048 K = 8 subchunks of 256 K),
//   with private double-buffered B-LDS + register prefetch 2 subchunks ahead.
//   One __syncthreads at the end, 4-way LDS reduce, single coalesced store.

typedef _Float16 half8 __attribute__((ext_vector_type(8)));
typedef float floatx16 __attribute__((ext_vector_type(16)));

union H2U { unsigned u; __half2 h; };
union V4H8 { uint4 u4; half8 h8; };

// (1024+n) exact -> -1024 -> -7.5  (all exact in f16)
__device__ __forceinline__ unsigned unpack_even(unsigned ws, __half2 c1, __half2 c2) {
    H2U t; t.u = (ws & 0x000F000Fu) | 0x64006400u;
    t.h = __hadd2(__hadd2(t.h, c1), c2);
    return t.u;
}
// (1024+16n) exact -> *1/16 - 71.5 = n - 7.5 (exact fma)
__device__ __forceinline__ unsigned unpack_odd(unsigned ws, __half2 cs, __half2 cc) {
    H2U t; t.u = (ws & 0x00F000F0u) | 0x64006400u;
    t.h = __hfma2(t.h, cs, cc);
    return t.u;
}

#define BPITCH 136                    // 32 words + 8B pad (2-way-free ds_read_b64)
#define BBUF   (32 * BPITCH)          // 4352 B, one B buffer (32 rows x 32 words)
#define APITCH 272                    // 16 slots x 16B + zero slot, 16B-aligned pitch
#define ATBL   (16 * APITCH)          // 4352 B, one A table (16 steps)
#define AB0    (4 * 2 * BBUF)         // 34816: B buffers (4 waves x 2)
#define RED0   (AB0 + 4 * ATBL)       // 52224: A tables (4 waves x 1)
#define LDS_BYTES (RED0 + 4096)       // 56320: + reduce area (4 waves x 8x32 f32)

__global__ __launch_bounds__(256)
void hi4b_gemm(const float* __restrict__ x, const int* __restrict__ q,
               float* __restrict__ out)
{
    extern __shared__ char lds[];
    const int tid  = threadIdx.x;
    const int lane = tid & 63;
    const int wv   = tid >> 6;          // K-quarter 0..3
    const int n0   = blockIdx.x * 32;

    const int nlo = lane & 31;
    const int u   = lane >> 5;
    const int c   = lane & 7;           // uint4 within row-subchunk
    const int r0  = lane >> 3;          // 0..7

    const uint4*  q4 = (const uint4*)q;     // 256 uint4 per n-row
    const float4* x4 = (const float4*)x;    // 2048 float4 per b-row

    const int qbase = (n0 + r0) * 256 + wv * 64 + c;
    const int slot = lane & 15, uu = slot >> 3, rr = slot & 7;
    const int xbase = rr * 2048 + wv * 512 + uu;
    const int shi = lane >> 4;              // s_i = 4*i + shi

    char* Bw = lds + wv * 2 * BBUF;
    char* Aw = lds + AB0 + wv * ATBL;

    // zero slot (A rows 8..31 are padding) — written once, never overwritten
    if (lane < 16)
        *(uint4*)(Aw + lane * APITCH + 256) = make_uint4(0u, 0u, 0u, 0u);

    uint4 rb0, rb1, rb2, rb3;
    float4 ra[8];

    auto loadB = [&](int sc) {
        int b = qbase + sc * 8;
        rb0 = q4[b];
        rb1 = q4[b +  8 * 256];
        rb2 = q4[b + 16 * 256];
        rb3 = q4[b + 24 * 256];
    };
    auto loadA = [&](int sc) {
        #pragma unroll
        for (int i = 0; i < 4; ++i) {
            int xi = xbase + sc * 64 + 4 * (4 * i + shi);
            ra[2 * i]     = x4[xi];
            ra[2 * i + 1] = x4[xi + 2];
        }
    };
    auto writeB = [&](int d) {
        char* Bb = Bw + d * BBUF;
        char* p0 = Bb + (r0     ) * BPITCH + c * 16;
        char* p1 = Bb + (r0 +  8) * BPITCH + c * 16;
        char* p2 = Bb + (r0 + 16) * BPITCH + c * 16;
        char* p3 = Bb + (r0 + 24) * BPITCH + c * 16;
        *(uint2*)(p0)     = make_uint2(rb0.x, rb0.y);
        *(uint2*)(p0 + 8) = make_uint2(rb0.z, rb0.w);
        *(uint2*)(p1)     = make_uint2(rb1.x, rb1.y);
        *(uint2*)(p1 + 8) = make_uint2(rb1.z, rb1.w);
        *(uint2*)(p2)     = make_uint2(rb2.x, rb2.y);
        *(uint2*)(p2 + 8) = make_uint2(rb2.z, rb2.w);
        *(uint2*)(p3)     = make_uint2(rb3.x, rb3.y);
        *(uint2*)(p3 + 8) = make_uint2(rb3.z, rb3.w);
    };
    auto writeA = [&]() {
        #pragma unroll
        for (int i = 0; i < 4; ++i) {
            H2U a0, a1, a2, a3;
            a0.h = __floats2half2_rn(ra[2*i].x,   ra[2*i].y);
            a1.h = __floats2half2_rn(ra[2*i].z,   ra[2*i].w);
            a2.h = __floats2half2_rn(ra[2*i+1].x, ra[2*i+1].y);
            a3.h = __floats2half2_rn(ra[2*i+1].z, ra[2*i+1].w);
            *(uint4*)(Aw + (4 * i + shi) * APITCH + slot * 16) =
                make_uint4(a0.u, a1.u, a2.u, a3.u);
        }
    };

    const __half2 c1 = __floats2half2_rn(-1024.0f, -1024.0f);
    const __half2 c2 = __floats2half2_rn(-7.5f, -7.5f);
    const __half2 cs = __floats2half2_rn(0.0625f, 0.0625f);
    const __half2 cc = __floats2half2_rn(-71.5f, -71.5f);

    floatx16 acc;
    #pragma unroll
    for (int i = 0; i < 16; ++i) acc[i] = 0.0f;

    const int sh = 8 * u;
    const char* apL = Aw + ((nlo < 8) ? (u * 8 + nlo) * 16 : 256);

    auto compute = [&](int d) {
        const char* bp = Bw + d * BBUF + nlo * BPITCH;
        #pragma unroll
        for (int s = 0; s < 16; ++s) {
            uint2 w2 = *(const uint2*)(bp + s * 8);
            V4H8 A;  A.u4 = *(const uint4*)(apL + s * APITCH);
            unsigned wsa = w2.x >> sh;
            unsigned wsb = w2.y >> sh;
            V4H8 Bf;
            Bf.u4.x = unpack_even(wsa, c1, c2);
            Bf.u4.y = unpack_odd (wsa, cs, cc);
            Bf.u4.z = unpack_even(wsb, c1, c2);
            Bf.u4.w = unpack_odd (wsb, cs, cc);
            acc = __builtin_amdgcn_mfma_f32_32x32x16_f16(A.h8, Bf.h8, acc, 0, 0, 0);
        }
    };

    // ---- pipelined main loop: loads 2 ahead (B), 1 ahead (A), no barriers ----
    loadB(0); loadA(0);
    writeB(0); writeA();            // tables for sc=0
    loadB(1); loadA(1);             // regs hold sc=1
    #pragma unroll
    for (int sc = 0; sc < 8; ++sc) {
        if (sc + 1 < 8) writeB((sc + 1) & 1);   // B(sc+1) into other buffer
        if (sc + 2 < 8) loadB(sc + 2);
        compute(sc & 1);                        // reads B(sc), A(sc)
        if (sc + 1 < 8) writeA();               // A(sc+1) into single table (after reads)
        if (sc + 2 < 8) loadA(sc + 2);
    }

    // ---- cross-wave reduce: wave tiles are 8 b-rows x 32 n-cols ----
    {
        float* red = (float*)(lds + RED0 + wv * 1024);
        #pragma unroll
        for (int r = 0; r < 4; ++r)
            red[(r + 4 * u) * 32 + nlo] = acc[r];
    }
    __syncthreads();
    {
        const int b = tid >> 5, nl = tid & 31;
        const float* rd = (const float*)(lds + RED0);
        float sm = rd[b * 32 + nl] + rd[256 + b * 32 + nl]
                 + rd[512 + b * 32 + nl] + rd[768 + b * 32 + nl];
        out[b * 8192 + n0 + nl] = sm;
    }
}

extern "C" void kernel_launch(void* const* d_in, const int* in_sizes, int n_in,
                              void* d_out, int out_size, void* d_ws, size_t ws_size,
                              hipStream_t stream)
{
    const float* x = (const float*)d_in[0];
    const int*   q = (const int*)d_in[1];
    float* out = (float*)d_out;

    hipLaunchKernelGGL(hi4b_gemm, dim3(256), dim3(256), LDS_BYTES, stream,
                       x, q, out);
}